// Round 9
// baseline (4357.912 us; speedup 1.0000x reference)
//
#include <hip/hip_runtime.h>
#include <stdint.h>

// Sizes: x [16,1,512,512] f32 binary; weight [1024,512] f32; out [16,1,1024,529] f32.
// pot[b,o,t'] = sum_tau K(w[o,i],tau) * x[b,i,t'+15-tau] + 12.8
// K via cumsum^2 of its Delta^2; tap pairs scattered at spike positions into per-wave
// LDS planes; WTA depression uniform -> per-batch serial scan.
// R12 lesson: random-scatter bank conflicts are layout-invariant (~8 cyc/b64 floor).
// R14 lesson: not conflict-bound (+20% conflicts, zero time delta); limiter is the
// ds_read->add->ds_write dependency chain at 3 blocks/CU of latency cover (LDS pipe 63%).
// R15 lesson: ds_pk_add_f32 is not a gfx950 instruction (compile error).
// R16: ds_add_f32 x2 (scalar no-return LDS float atomic, offset:4 for v2) --
// fire-and-forget, NO dependency chain, explicit lgkmcnt(0) drain before the barrier
// (asm DS ops are untracked by compiler waitcnt; DS completes in-order so compiler's
// own counted waits stay conservative). Atomics => ramp planes MERGE: LDS 40.9K ->
// 22.1K => 7 blocks/CU. Guard e8 < 561*8 exec-masks sentinel spikes (t8=0xFFF8) and
// missing pairs (p8=16384); masked lanes cost no bank cycles.
// R17/R18: identical resubmits -- R16/R17 benches were infra failures (no timing block
// => failed before staging; kernel never compiled). R1/R3 showed same pattern.

#define NB 16
#define NI 512
#define NT 512
#define NO 1024
#define TOUT 529
#define SCAP 96           // spike capacity per (b,i); max observed ~48
#define OTILE 4
#define PLANE 562         // float2 cells 0..560 live; 562 for float4-divisible init
#define EMAX8 4488        // 561*8: first invalid byte offset
#define THETA_F 25.6f
#define BIAS_T 12.8f

// ---------- P1: spike list (LDS-staged) + packed byte-scaled words + counts + hist ----------
__global__ __launch_bounds__(256) void k_spikes(const float* __restrict__ x,
                                                unsigned short* __restrict__ slist,
                                                unsigned int* __restrict__ spkw,
                                                unsigned int* __restrict__ counts,
                                                float* __restrict__ hg) {
    __shared__ unsigned short sls[4][SCAP];
    int wq = threadIdx.x >> 6, lane = threadIdx.x & 63;
    int row = blockIdx.x * 4 + wq;                 // row = b*512 + i
    int b = row >> 9;
    const float* xr = x + (size_t)row * NT;
    for (int j = lane; j < SCAP; j += 64) sls[wq][j] = 0x1FFF;   // 0x1FFF<<3 = 0xFFF8 sentinel
    int base = 0;
    for (int kk = 0; kk < 8; ++kk) {
        int t = kk * 64 + lane;
        bool pred = xr[t] > 0.5f;
        unsigned long long mask = __ballot(pred);
        int pre = __popcll(mask & ((1ull << lane) - 1ull));
        int pos = base + pre;
        if (pred) {
            if (pos < SCAP) sls[wq][pos] = (unsigned short)t;
            unsafeAtomicAdd(&hg[b * NT + t], 1.0f);   // integer counts: exact any order
        }
        base += __popcll(mask);
    }
    __syncthreads();
    if (lane < SCAP / 2) {                         // full raw list for cold path
        unsigned v = (unsigned)sls[wq][2 * lane] | ((unsigned)sls[wq][2 * lane + 1] << 16);
        ((unsigned int*)(slist + (size_t)row * SCAP))[lane] = v;
    }
    if (lane < 32)                                 // packed (k, k+32) pair words, BYTE-scaled
        spkw[(size_t)row * 32 + lane] =
            ((unsigned)sls[wq][lane] << 3) | ((unsigned)sls[wq][lane + 32] << 19);
    if (lane == 0) counts[row] = (unsigned)min(base, SCAP);
}

// ---------- P2: per-(o,i) taps via candidate ranges (bit-identical to 50-iter loop) ----------
// tap[((o*512+i)*2 + ramp)] = float4(v1, v2, pos8_as_int_bits, 0). Missing pair: pos8=16384.
__device__ __forceinline__ float kval(float b15, int tau) {
    if (tau > 47) return 0.f;
    float f = (float)tau * 0.0625f;
    float g = b15 - (float)tau * 0.03125f;
    return fmaxf(0.f, fminf(f, g));
}

__global__ __launch_bounds__(256) void k_taps(const float* __restrict__ weight,
                                              float4* __restrict__ tap) {
    int p = blockIdx.x * 256 + threadIdx.x;        // 512*1024; i fast -> coalesced
    int o = p >> 9, i = p & 511;
    float w = weight[o * NI + i];
    float b15 = 1.5f * w;
    float vA1 = 0.f, vA2 = 0.f, vB1 = 0.f, vB2 = 0.f;
    int posA = 2048, posB = 2048, state = 0;
    // d(tau) nonzero only near the two kinks s1=16w, s2=48w (+-1 widened) and onset.
    int n1 = (int)floorf(16.0f * w);
    int n2 = (int)floorf(48.0f * w);
    int lo1 = max(n1, 1);
    int hi1, lo2, hi2;
    if (n2 <= n1 + 4) { hi1 = min(n2 + 3, 49); lo2 = 1; hi2 = 0; }   // merged, range2 empty
    else             { hi1 = min(n1 + 3, 49); lo2 = n2; hi2 = min(n2 + 3, 49); }

#define TAPRUN(LO, HI)                                                                \
    {                                                                                 \
        float Km1 = kval(b15, (LO) - 1), Km2 = kval(b15, (LO) - 2);                   \
        for (int tau = (LO); tau <= (HI); ++tau) {                                    \
            float K = kval(b15, tau);                                                 \
            float d = (K - Km1) - (Km1 - Km2);                                        \
            if (tau == 1) d -= 0.0625f;            /* onset -> histogram */           \
            if (d != 0.f) {                                                           \
                if (state == 0)      { posA = tau; vA1 = d; state = 1; }              \
                else if (state == 1) { if (tau == posA + 1) { vA2 = d; state = 2; }   \
                                       else { posB = tau; vB1 = d; state = 3; } }     \
                else if (state == 2) { posB = tau; vB1 = d; state = 3; }              \
                else if (state == 3) { if (tau == posB + 1) { vB2 = d; state = 4; } } \
            }                                                                         \
            Km2 = Km1; Km1 = K;                                                       \
        }                                                                             \
    }
    TAPRUN(lo1, hi1)
    if (lo2 <= hi2) TAPRUN(lo2, hi2)

    size_t base = 2 * ((size_t)o * NI + i);
    tap[base]     = make_float4(vA1, vA2, __int_as_float(posA >= 2048 ? 16384 : posA * 8), 0.f);
    tap[base + 1] = make_float4(vB1, vB2, __int_as_float(posB >= 2048 ? 16384 : posB * 8), 0.f);
}

// ---------- P3: per-wave-plane ds_add_f32 scatter + fused double cumsum^2 ----------
// Wave w owns ONE float2 plane (atomics => no per-ramp split). Lane: k=lane>>1 spike
// slot, ramp=lane&1 pair (A/B). Two no-return ds_add_f32 add (v1,v2) to cell e
// (v2 via offset:4); v2 consumed with +1 shift at cumsum read. Guard e8<EMAX8
// exec-masks missing spikes (t8=0xFFF8) and missing pairs (p8=16384).
__device__ __forceinline__ void lds_add2(unsigned addr, float vx, float vy) {
    asm volatile("ds_add_f32 %0, %1\n\t"
                 "ds_add_f32 %0, %2 offset:4" :: "v"(addr), "v"(vx), "v"(vy));
}

#define PROC(TP, WV, CNT, IDX)                                                        \
    {                                                                                 \
        const int p8 = __float_as_int((TP).z);                                        \
        {                                                                             \
            int e8 = (int)((WV) & 0xFFFFu) + p8;                                      \
            if (e8 < EMAX8) lds_add2(accw_base + (unsigned)e8, (TP).x, (TP).y);       \
        }                                                                             \
        if ((CNT) > 32u) {                                                            \
            int e8 = (int)((WV) >> 16) + p8;                                          \
            if (e8 < EMAX8) lds_add2(accw_base + (unsigned)e8, (TP).x, (TP).y);       \
        }                                                                             \
        if ((CNT) > 64u) {                                                            \
            const unsigned short* sr = slist + (size_t)(b * NI + (IDX)) * SCAP;       \
            for (int kk = 64 + k; kk < (int)(CNT); kk += 32) {                        \
                int e8 = ((int)sr[kk] << 3) + p8;                                     \
                if (e8 < EMAX8) lds_add2(accw_base + (unsigned)e8, (TP).x, (TP).y);   \
            }                                                                         \
        }                                                                             \
    }

__global__ __launch_bounds__(256, 7) void k_scatter(const unsigned short* __restrict__ slist,
                                                    const unsigned int* __restrict__ spkw,
                                                    const unsigned int* __restrict__ counts,
                                                    const float4* __restrict__ tap,
                                                    const float* __restrict__ hg,
                                                    float* __restrict__ pot) {
    __shared__ __align__(16) float2 acc[OTILE * PLANE];      // 17,984 B
    __shared__ double pub[512];                              // 4,096 B -> ~22.1 KB: 7 blk/CU
    const int o0 = blockIdx.x * OTILE;
    const int b  = blockIdx.y;
    const int tid = threadIdx.x;
    const int w = tid >> 6, lane = tid & 63;
    const int k = lane >> 1, ramp = lane & 1;

    for (int idx = tid; idx < OTILE * PLANE / 2; idx += 256)     // 1124 float4s = whole acc
        ((float4*)acc)[idx] = make_float4(0.f, 0.f, 0.f, 0.f);
    __syncthreads();

    const unsigned accw_base = (unsigned)(uintptr_t)(acc + w * PLANE);   // LDS byte offset
    const unsigned int* wrow = spkw + (size_t)(b * NI) * 32 + k;
    const float4* trow = tap + 2 * (size_t)(o0 + w) * NI + ramp;
    const uint4* crow = (const uint4*)(counts + b * NI);

    // prefetch quad 0 (statically-named scalars -> registers; R9 lesson)
    float4 ntA = trow[0], ntB = trow[2], ntC = trow[4], ntD = trow[6];
    unsigned nwA = wrow[0], nwB = wrow[32], nwC = wrow[64], nwD = wrow[96];
    uint4 ncc = crow[0];

    const int NIQ = NI / 4;
    for (int iq = 0; iq < NIQ; ++iq) {
        const float4 tA = ntA, tB = ntB, tC = ntC, tD = ntD;
        const unsigned wA = nwA, wB = nwB, wC = nwC, wD = nwD;
        const uint4 cc = ncc;
        if (iq + 1 < NIQ) {                        // prefetch next quad
            const float4* tb = trow + (size_t)(iq + 1) * 8;
            ntA = tb[0]; ntB = tb[2]; ntC = tb[4]; ntD = tb[6];
            const unsigned int* wb = wrow + (size_t)(iq + 1) * 128;
            nwA = wb[0]; nwB = wb[32]; nwC = wb[64]; nwD = wb[96];
            ncc = crow[iq + 1];
        }
        const int i0 = iq * 4;
        PROC(tA, wA, cc.x, i0)
        PROC(tB, wB, cc.y, i0 + 1)
        PROC(tC, wC, cc.z, i0 + 2)
        PROC(tD, wD, cc.w, i0 + 3)
    }
    // Drain our untracked asm DS atomics, then barrier (DS completes in-order, so the
    // compiler's own counted lgkm waits elsewhere remain conservative/correct).
    asm volatile("s_waitcnt lgkmcnt(0)" ::: "memory");
    __syncthreads();

    // ---- cumsum^2 (double): thread (oo=w, q=lane) owns cells [9q, 9q+9) ----
    const int q = lane;
    const float2* pr = acc + w * PLANE;
    const float* hb = hg + b * NT;
    double dsv[9];
    double s1d = 0.0, s2d = 0.0;
#pragma unroll
    for (int r = 0; r < 9; ++r) {
        int e = q * 9 + r;
        double d = 0.0;
        if (e < 561) {
            d = (double)pr[e].x;
            if (e >= 1) {
                d += (double)pr[e - 1].y;                        // v2: shifted +1
                if (e <= 512) d += 0.0625 * (double)hb[e - 1];   // onset histogram
            }
        }
        dsv[r] = d; s1d += d; s2d += s1d;
    }
    pub[2 * tid] = s1d; pub[2 * tid + 1] = s2d;
    __syncthreads();
    if (tid < 4) {                                 // serial carry scan per o-row
        double c1 = 0.0, c2 = 0.0;
        for (int qq = 0; qq < 64; ++qq) {
            int j = (tid << 6) + qq;
            double S1 = pub[2 * j], S2 = pub[2 * j + 1];
            pub[2 * j] = c1; pub[2 * j + 1] = c2;
            c2 += 9.0 * c1 + S2;
            c1 += S1;
        }
    }
    __syncthreads();
    {
        const double C1 = pub[2 * tid], C2 = pub[2 * tid + 1];
        double a1 = 0.0, a2 = 0.0;
        float2* rowW = acc + w * PLANE;
#pragma unroll
        for (int r = 0; r < 9; ++r) {
            a1 += dsv[r]; a2 += a1;
            int e = q * 9 + r;
            if (e < 561) rowW[e].x = (float)(C2 + C1 * (double)(r + 1) + a2);
        }
    }
    __syncthreads();
    for (int oo = 0; oo < OTILE; ++oo)             // coalesced pot write (t fastest)
        for (int t = tid; t < TOUT; t += 256)
            pot[((size_t)(b * NO + o0 + oo)) * TOUT + t] = acc[oo * PLANE + t + 15].x + BIAS_T;
}

// ---------- P4a: partial argmax over 128-o chunks (1152 blocks) ----------
__global__ __launch_bounds__(256) void k_argmax1(const float* __restrict__ pot,
                                                 float* __restrict__ pval,
                                                 unsigned short* __restrict__ pidx) {
    __shared__ float sv[4][64];
    __shared__ int   si[4][64];
    int b = blockIdx.y, c = blockIdx.z;
    int lane = threadIdx.x & 63, grp = threadIdx.x >> 6;
    int t = blockIdx.x * 64 + lane;
    bool valid = t < TOUT;
    float best = -1.f; int bidx = 0;
    if (valid) {
        int ob = c * 128 + grp * 32;
        for (int od = 0; od < 32; ++od) {          // ascending o + strict '>' => first max wins
            int o = ob + od;
            float v = pot[((size_t)(b * NO + o)) * TOUT + t];
            if (v > best) { best = v; bidx = o; }
        }
    }
    sv[grp][lane] = best; si[grp][lane] = bidx;
    __syncthreads();
    if (grp == 0 && valid) {
#pragma unroll
        for (int g = 1; g < 4; ++g) {              // ascending grp = ascending o
            float v = sv[g][lane];
            if (v > best) { best = v; bidx = si[g][lane]; }
        }
        pval[((size_t)(c * NB + b)) * TOUT + t] = best;
        pidx[((size_t)(c * NB + b)) * TOUT + t] = (unsigned short)bidx;
    }
}

// ---------- P4b: combine 8 chunks ----------
__global__ __launch_bounds__(64) void k_argmax2(const float* __restrict__ pval,
                                                const unsigned short* __restrict__ pidx,
                                                float* __restrict__ aval,
                                                unsigned short* __restrict__ aidx) {
    int b = blockIdx.y;
    int t = blockIdx.x * 64 + threadIdx.x;
    if (t >= TOUT) return;
    float best = -1.f; int bidx = 0;
#pragma unroll
    for (int c = 0; c < 8; ++c) {                  // ascending chunk = ascending o
        size_t idx = ((size_t)(c * NB + b)) * TOUT + t;
        float v = pval[idx];
        if (v > best) { best = v; bidx = pidx[idx]; }
    }
    aval[t * NB + b] = best;
    aidx[t * NB + b] = (unsigned short)bidx;
}

// ---------- P5: serial refractory scan (depression uniform across neurons) ----------
__global__ __launch_bounds__(256) void k_wta(const float* __restrict__ aval,
                                             const unsigned short* __restrict__ aidx,
                                             float* __restrict__ out) {
    __shared__ float lv[TOUT * NB];
    __shared__ unsigned short li[TOUT * NB];
    for (int idx = threadIdx.x; idx < TOUT * NB; idx += 256) { lv[idx] = aval[idx]; li[idx] = aidx[idx]; }
    __syncthreads();
    int b = threadIdx.x;
    if (b < NB) {
        int r = 0;
        for (int t = 0; t < TOUT; ++t) {
            float v = lv[t * NB + b];
            if (r == 0 && v > THETA_F) {
                int n = (int)li[t * NB + b];
                out[((size_t)(b * NO + n)) * TOUT + t] = 1.0f;
                r = 48;
            }
            r = max(r - 1, 0);
        }
    }
}

extern "C" void kernel_launch(void* const* d_in, const int* in_sizes, int n_in,
                              void* d_out, int out_size, void* d_ws, size_t ws_size,
                              hipStream_t stream) {
    const float* x      = (const float*)d_in[0];   // [16,1,512,512]
    const float* weight = (const float*)d_in[1];   // [1024,512]
    float* out = (float*)d_out;                    // [16,1,1024,529]
    char* ws = (char*)d_ws;
    // ws layout (~19.9 MB)
    unsigned short* slist  = (unsigned short*)(ws);            // 8192*96*2     = 1,572,864
    unsigned int*   spkw   = (unsigned int*)(ws + 1572864);    // 8192*32*4     = 1,048,576
    unsigned int*   counts = (unsigned int*)(ws + 2621440);    // 8192*4        = 32,768
    float4*         tap    = (float4*)(ws + 2654208);          // 1024*512*2*16 = 16,777,216
    float*          hg     = (float*)(ws + 19431424);          // 16*512*4      = 32,768
    float*          aval   = (float*)(ws + 19464192);          // 529*16*4      = 33,856
    unsigned short* aidx   = (unsigned short*)(ws + 19498048); // 529*16*2      = 16,928
    float*          pval   = (float*)(ws + 19514976);          // 8*16*529*4    = 270,848
    unsigned short* pidx   = (unsigned short*)(ws + 19785824); // 8*16*529*2    = 135,424

    hipMemsetAsync(hg, 0, NB * NT * sizeof(float), stream);    // before k_spikes (hist fused)
    k_spikes<<<2048, 256, 0, stream>>>(x, slist, spkw, counts, hg);
    k_taps<<<2048, 256, 0, stream>>>(weight, tap);
    k_scatter<<<dim3(NO / OTILE, NB), 256, 0, stream>>>(slist, spkw, counts, tap, hg, out);
    k_argmax1<<<dim3(9, NB, 8), 256, 0, stream>>>(out, pval, pidx);
    k_argmax2<<<dim3(9, NB), 64, 0, stream>>>(pval, pidx, aval, aidx);
    hipMemsetAsync(d_out, 0, (size_t)out_size * sizeof(float), stream);   // clear pot
    k_wta<<<1, 256, 0, stream>>>(aval, aidx, out);                        // write spikes
}

// Round 10
// 682.385 us; speedup vs baseline: 6.3863x; 6.3863x over previous
//
#include <hip/hip_runtime.h>
#include <stdint.h>

// Sizes: x [16,1,512,512] f32 binary; weight [1024,512] f32; out [16,1,1024,529] f32.
// pot[b,o,t'] = sum_tau K(w[o,i],tau) * x[b,i,t'+15-tau] + 12.8
// K via cumsum^2 of its Delta^2; tap pairs scattered at spike positions into per-wave
// LDS planes; WTA depression uniform -> per-batch serial scan.
// R12: random-scatter bank conflicts are layout-invariant (~8 cyc/b64 floor).
// R14: not conflict-bound; limiter = ds_read->add->ds_write chains at 3 blk/CU cover.
// R16 (measured): LDS float atomics serialize PER LANE (~78 cyc/ds_add_f32) -> 11.7x
// slower. Atomics are dead; non-atomic b64 RMW is the fast path.
// R19: occupancy attack keeping the non-atomic RMW. (1) ONE plane per wave: lane=slot
// (64 slots, distinct t, wave-uniform p) -> intra-instruction cells distinct; ramp-A
// and ramp-B RMWs sequential (compiler alias-ordering makes overlap correct).
// (2) block = one o, 4 waves x 128 i: taps/counts wave-uniform (readfirstlane ->
// s_load); spike word = only per-lane VMEM. (3) pub scratch overlaid on dead plane-0
// cells. LDS 17,984 B -> 8 blocks/CU (32 waves) vs 3.

#define NB 16
#define NI 512
#define NT 512
#define NO 1024
#define TOUT 529
#define SCAP 96           // spike capacity per (b,i); max observed ~48
#define IPW 128           // i's per wave (4 waves x 128 = 512)
#define PLANE 562         // float2 cells 0..560 live; 562 for float4-divisible init
#define EMAX8 4488        // 561*8: first invalid byte offset
#define THETA_F 25.6f
#define BIAS_T 12.8f

// ---------- P1: spike list (LDS-staged) + packed byte-scaled words + counts + hist ----------
__global__ __launch_bounds__(256) void k_spikes(const float* __restrict__ x,
                                                unsigned short* __restrict__ slist,
                                                unsigned int* __restrict__ spkw,
                                                unsigned int* __restrict__ counts,
                                                float* __restrict__ hg) {
    __shared__ unsigned short sls[4][SCAP];
    int wq = threadIdx.x >> 6, lane = threadIdx.x & 63;
    int row = blockIdx.x * 4 + wq;                 // row = b*512 + i
    int b = row >> 9;
    const float* xr = x + (size_t)row * NT;
    for (int j = lane; j < SCAP; j += 64) sls[wq][j] = 0x1FFF;   // 0x1FFF<<3 = 0xFFF8 sentinel
    int base = 0;
    for (int kk = 0; kk < 8; ++kk) {
        int t = kk * 64 + lane;
        bool pred = xr[t] > 0.5f;
        unsigned long long mask = __ballot(pred);
        int pre = __popcll(mask & ((1ull << lane) - 1ull));
        int pos = base + pre;
        if (pred) {
            if (pos < SCAP) sls[wq][pos] = (unsigned short)t;
            unsafeAtomicAdd(&hg[b * NT + t], 1.0f);   // integer counts: exact any order
        }
        base += __popcll(mask);
    }
    __syncthreads();
    if (lane < SCAP / 2) {                         // full raw list for cold path
        unsigned v = (unsigned)sls[wq][2 * lane] | ((unsigned)sls[wq][2 * lane + 1] << 16);
        ((unsigned int*)(slist + (size_t)row * SCAP))[lane] = v;
    }
    if (lane < 32)                                 // packed (k, k+32) pair words, BYTE-scaled
        spkw[(size_t)row * 32 + lane] =
            ((unsigned)sls[wq][lane] << 3) | ((unsigned)sls[wq][lane + 32] << 19);
    if (lane == 0) counts[row] = (unsigned)min(base, SCAP);
}

// ---------- P2: per-(o,i) taps via candidate ranges (bit-identical to 50-iter loop) ----------
// tap[((o*512+i)*2 + ramp)] = float4(v1, v2, pos8_as_int_bits, 0). Missing pair: pos8=16384.
__device__ __forceinline__ float kval(float b15, int tau) {
    if (tau > 47) return 0.f;
    float f = (float)tau * 0.0625f;
    float g = b15 - (float)tau * 0.03125f;
    return fmaxf(0.f, fminf(f, g));
}

__global__ __launch_bounds__(256) void k_taps(const float* __restrict__ weight,
                                              float4* __restrict__ tap) {
    int p = blockIdx.x * 256 + threadIdx.x;        // 512*1024; i fast -> coalesced
    int o = p >> 9, i = p & 511;
    float w = weight[o * NI + i];
    float b15 = 1.5f * w;
    float vA1 = 0.f, vA2 = 0.f, vB1 = 0.f, vB2 = 0.f;
    int posA = 2048, posB = 2048, state = 0;
    // d(tau) nonzero only near the two kinks s1=16w, s2=48w (+-1 widened) and onset.
    int n1 = (int)floorf(16.0f * w);
    int n2 = (int)floorf(48.0f * w);
    int lo1 = max(n1, 1);
    int hi1, lo2, hi2;
    if (n2 <= n1 + 4) { hi1 = min(n2 + 3, 49); lo2 = 1; hi2 = 0; }   // merged, range2 empty
    else             { hi1 = min(n1 + 3, 49); lo2 = n2; hi2 = min(n2 + 3, 49); }

#define TAPRUN(LO, HI)                                                                \
    {                                                                                 \
        float Km1 = kval(b15, (LO) - 1), Km2 = kval(b15, (LO) - 2);                   \
        for (int tau = (LO); tau <= (HI); ++tau) {                                    \
            float K = kval(b15, tau);                                                 \
            float d = (K - Km1) - (Km1 - Km2);                                        \
            if (tau == 1) d -= 0.0625f;            /* onset -> histogram */           \
            if (d != 0.f) {                                                           \
                if (state == 0)      { posA = tau; vA1 = d; state = 1; }              \
                else if (state == 1) { if (tau == posA + 1) { vA2 = d; state = 2; }   \
                                       else { posB = tau; vB1 = d; state = 3; } }     \
                else if (state == 2) { posB = tau; vB1 = d; state = 3; }              \
                else if (state == 3) { if (tau == posB + 1) { vB2 = d; state = 4; } } \
            }                                                                         \
            Km2 = Km1; Km1 = K;                                                       \
        }                                                                             \
    }
    TAPRUN(lo1, hi1)
    if (lo2 <= hi2) TAPRUN(lo2, hi2)

    size_t base = 2 * ((size_t)o * NI + i);
    tap[base]     = make_float4(vA1, vA2, __int_as_float(posA >= 2048 ? 16384 : posA * 8), 0.f);
    tap[base + 1] = make_float4(vB1, vB2, __int_as_float(posB >= 2048 ? 16384 : posB * 8), 0.f);
}

// ---------- P3: one-plane-per-wave non-atomic RMW scatter + fused double cumsum^2 ----------
// Block = one o; wave w handles i in [w*128, w*128+128), own plane (562 float2).
// Lane = slot: 64 lanes cover all <=64 spike slots of one i at once; ramp-A RMW then
// ramp-B RMW (sequential; compiler alias-ordering => overlap-correct). Intra-instruction
// cells distinct (distinct t, wave-uniform p). Guard e8<EMAX8 exec-masks sentinel slots
// (t8=0xFFF8) and missing pairs (p8=16384). pub carry-scan scratch overlays dead plane-0
// cells after dsv extraction (barrier-fenced).
__global__ __launch_bounds__(256, 8) void k_scatter(const unsigned short* __restrict__ slist,
                                                    const unsigned int* __restrict__ spkw,
                                                    const unsigned int* __restrict__ counts,
                                                    const float4* __restrict__ tap,
                                                    const float* __restrict__ hg,
                                                    float* __restrict__ pot) {
    __shared__ __align__(16) float2 acc[4 * PLANE];          // 17,984 B -> 8 blocks/CU
    const int o = blockIdx.x;
    const int b = blockIdx.y;
    const int tid = threadIdx.x;
    const int w = tid >> 6, lane = tid & 63;

    for (int idx = tid; idx < 4 * PLANE / 2; idx += 256)     // 1124 float4s = whole acc
        ((float4*)acc)[idx] = make_float4(0.f, 0.f, 0.f, 0.f);
    __syncthreads();

    float2* plane = acc + w * PLANE;
    const int i0u = __builtin_amdgcn_readfirstlane(w * IPW); // wave-uniform -> s_load taps
    const float4* tw = tap + 2 * ((size_t)o * NI + i0u);
    const unsigned int* wr = spkw + ((size_t)(b * NI + i0u)) * 32 + (lane & 31);
    const unsigned int* cnts = counts + (b * NI + i0u);
    const int half = (lane >> 5) * 16;

    // 1-deep named prefetch (R9 lesson: static names -> registers)
    float4 tAn = tw[0], tBn = tw[1];
    unsigned wvn = wr[0];
    for (int ii = 0; ii < IPW; ++ii) {
        const float4 tA = tAn, tB = tBn;
        const unsigned wv = wvn;
        if (ii + 1 < IPW) {
            tAn = tw[2 * (ii + 1)];
            tBn = tw[2 * (ii + 1) + 1];
            wvn = wr[(size_t)(ii + 1) * 32];
        }
        const int t8 = (int)((wv >> half) & 0xFFFFu);
        const int pA8 = __float_as_int(tA.z);
        const int pB8 = __float_as_int(tB.z);
        int eA8 = t8 + pA8;
        if (eA8 < EMAX8) {
            float2* c = (float2*)((char*)plane + eA8);
            float2 v = *c; v.x += tA.x; v.y += tA.y; *c = v;
        }
        int eB8 = t8 + pB8;
        if (eB8 < EMAX8) {
            float2* c = (float2*)((char*)plane + eB8);
            float2 v = *c; v.x += tB.x; v.y += tB.y; *c = v;
        }
        const unsigned cnt = cnts[ii];             // uniform; overflow path ~never taken
        if (cnt > 64u) {
            const unsigned short* sr = slist + (size_t)(b * NI + i0u + ii) * SCAP;
            for (int kk = 64 + lane; kk < (int)cnt; kk += 64) {
                int t8o = (int)sr[kk] << 3;
                int e1 = t8o + pA8;
                if (e1 < EMAX8) { float2* c = (float2*)((char*)plane + e1);
                                  float2 v = *c; v.x += tA.x; v.y += tA.y; *c = v; }
                int e2 = t8o + pB8;
                if (e2 < EMAX8) { float2* c = (float2*)((char*)plane + e2);
                                  float2 v = *c; v.x += tB.x; v.y += tB.y; *c = v; }
            }
        }
    }
    __syncthreads();

    // ---- cumsum^2 (double): thread tid owns global cells [3*tid, 3*tid+3) ----
    const float* hb = hg + b * NT;
    double dsv[3];
    double s1d = 0.0, s2d = 0.0;
    const int c0 = tid * 3;
#pragma unroll
    for (int r = 0; r < 3; ++r) {
        int e = c0 + r;
        double d = 0.0;
        if (e < 561) {
            d = (double)acc[e].x + (double)acc[PLANE + e].x
              + (double)acc[2 * PLANE + e].x + (double)acc[3 * PLANE + e].x;
            if (e >= 1) {
                d += (double)acc[e - 1].y + (double)acc[PLANE + e - 1].y
                   + (double)acc[2 * PLANE + e - 1].y + (double)acc[3 * PLANE + e - 1].y;
                if (e <= 512) d += 0.0625 * (double)hb[e - 1];   // onset histogram
            }
        }
        dsv[r] = d; s1d += d; s2d += s1d;
    }
    __syncthreads();                               // all dsv reads done before pub overlay
    double* pub = (double*)acc;                    // overlays plane-0 cells 0..511 (dead)
    pub[2 * tid] = s1d; pub[2 * tid + 1] = s2d;
    __syncthreads();
    if (tid == 0) {                                // serial carry scan (one o per block)
        double c1 = 0.0, c2 = 0.0;
        for (int j = 0; j < 256; ++j) {
            double S1 = pub[2 * j], S2 = pub[2 * j + 1];
            pub[2 * j] = c1; pub[2 * j + 1] = c2;
            c2 += 3.0 * c1 + S2;
            c1 += S1;
        }
    }
    __syncthreads();
    const double C1 = pub[2 * tid], C2 = pub[2 * tid + 1];
    __syncthreads();                               // pub reads done before .x writes clobber
    {
        double a1 = 0.0, a2 = 0.0;
#pragma unroll
        for (int r = 0; r < 3; ++r) {
            a1 += dsv[r]; a2 += a1;
            int e = c0 + r;
            if (e < 561) acc[e].x = (float)(C2 + C1 * (double)(r + 1) + a2);
        }
    }
    __syncthreads();
    for (int t = tid; t < TOUT; t += 256)          // coalesced pot write (t fastest)
        pot[((size_t)(b * NO + o)) * TOUT + t] = acc[t + 15].x + BIAS_T;
}

// ---------- P4a: partial argmax over 128-o chunks (1152 blocks) ----------
__global__ __launch_bounds__(256) void k_argmax1(const float* __restrict__ pot,
                                                 float* __restrict__ pval,
                                                 unsigned short* __restrict__ pidx) {
    __shared__ float sv[4][64];
    __shared__ int   si[4][64];
    int b = blockIdx.y, c = blockIdx.z;
    int lane = threadIdx.x & 63, grp = threadIdx.x >> 6;
    int t = blockIdx.x * 64 + lane;
    bool valid = t < TOUT;
    float best = -1.f; int bidx = 0;
    if (valid) {
        int ob = c * 128 + grp * 32;
        for (int od = 0; od < 32; ++od) {          // ascending o + strict '>' => first max wins
            int o = ob + od;
            float v = pot[((size_t)(b * NO + o)) * TOUT + t];
            if (v > best) { best = v; bidx = o; }
        }
    }
    sv[grp][lane] = best; si[grp][lane] = bidx;
    __syncthreads();
    if (grp == 0 && valid) {
#pragma unroll
        for (int g = 1; g < 4; ++g) {              // ascending grp = ascending o
            float v = sv[g][lane];
            if (v > best) { best = v; bidx = si[g][lane]; }
        }
        pval[((size_t)(c * NB + b)) * TOUT + t] = best;
        pidx[((size_t)(c * NB + b)) * TOUT + t] = (unsigned short)bidx;
    }
}

// ---------- P4b: combine 8 chunks ----------
__global__ __launch_bounds__(64) void k_argmax2(const float* __restrict__ pval,
                                                const unsigned short* __restrict__ pidx,
                                                float* __restrict__ aval,
                                                unsigned short* __restrict__ aidx) {
    int b = blockIdx.y;
    int t = blockIdx.x * 64 + threadIdx.x;
    if (t >= TOUT) return;
    float best = -1.f; int bidx = 0;
#pragma unroll
    for (int c = 0; c < 8; ++c) {                  // ascending chunk = ascending o
        size_t idx = ((size_t)(c * NB + b)) * TOUT + t;
        float v = pval[idx];
        if (v > best) { best = v; bidx = pidx[idx]; }
    }
    aval[t * NB + b] = best;
    aidx[t * NB + b] = (unsigned short)bidx;
}

// ---------- P5: serial refractory scan (depression uniform across neurons) ----------
__global__ __launch_bounds__(256) void k_wta(const float* __restrict__ aval,
                                             const unsigned short* __restrict__ aidx,
                                             float* __restrict__ out) {
    __shared__ float lv[TOUT * NB];
    __shared__ unsigned short li[TOUT * NB];
    for (int idx = threadIdx.x; idx < TOUT * NB; idx += 256) { lv[idx] = aval[idx]; li[idx] = aidx[idx]; }
    __syncthreads();
    int b = threadIdx.x;
    if (b < NB) {
        int r = 0;
        for (int t = 0; t < TOUT; ++t) {
            float v = lv[t * NB + b];
            if (r == 0 && v > THETA_F) {
                int n = (int)li[t * NB + b];
                out[((size_t)(b * NO + n)) * TOUT + t] = 1.0f;
                r = 48;
            }
            r = max(r - 1, 0);
        }
    }
}

extern "C" void kernel_launch(void* const* d_in, const int* in_sizes, int n_in,
                              void* d_out, int out_size, void* d_ws, size_t ws_size,
                              hipStream_t stream) {
    const float* x      = (const float*)d_in[0];   // [16,1,512,512]
    const float* weight = (const float*)d_in[1];   // [1024,512]
    float* out = (float*)d_out;                    // [16,1,1024,529]
    char* ws = (char*)d_ws;
    // ws layout (~19.9 MB)
    unsigned short* slist  = (unsigned short*)(ws);            // 8192*96*2     = 1,572,864
    unsigned int*   spkw   = (unsigned int*)(ws + 1572864);    // 8192*32*4     = 1,048,576
    unsigned int*   counts = (unsigned int*)(ws + 2621440);    // 8192*4        = 32,768
    float4*         tap    = (float4*)(ws + 2654208);          // 1024*512*2*16 = 16,777,216
    float*          hg     = (float*)(ws + 19431424);          // 16*512*4      = 32,768
    float*          aval   = (float*)(ws + 19464192);          // 529*16*4      = 33,856
    unsigned short* aidx   = (unsigned short*)(ws + 19498048); // 529*16*2      = 16,928
    float*          pval   = (float*)(ws + 19514976);          // 8*16*529*4    = 270,848
    unsigned short* pidx   = (unsigned short*)(ws + 19785824); // 8*16*529*2    = 135,424

    hipMemsetAsync(hg, 0, NB * NT * sizeof(float), stream);    // before k_spikes (hist fused)
    k_spikes<<<2048, 256, 0, stream>>>(x, slist, spkw, counts, hg);
    k_taps<<<2048, 256, 0, stream>>>(weight, tap);
    k_scatter<<<dim3(NO, NB), 256, 0, stream>>>(slist, spkw, counts, tap, hg, out);
    k_argmax1<<<dim3(9, NB, 8), 256, 0, stream>>>(out, pval, pidx);
    k_argmax2<<<dim3(9, NB), 64, 0, stream>>>(pval, pidx, aval, aidx);
    hipMemsetAsync(d_out, 0, (size_t)out_size * sizeof(float), stream);   // clear pot
    k_wta<<<1, 256, 0, stream>>>(aval, aidx, out);                        // write spikes
}

// Round 11
// 528.661 us; speedup vs baseline: 8.2433x; 1.2908x over previous
//
#include <hip/hip_runtime.h>
#include <stdint.h>

// Sizes: x [16,1,512,512] f32 binary; weight [1024,512] f32; out [16,1,1024,529] f32.
// pot[b,o,t'] = sum_tau K(w[o,i],tau) * x[b,i,t'+15-tau] + 12.8
// K via cumsum^2 of its Delta^2; tap pairs scattered at spike positions into per-(wave,ramp)
// float2 LDS planes; WTA depression uniform -> per-batch serial scan.
// R12: random-scatter bank conflicts are layout-invariant (~8 cyc/b64 floor).
// R16: LDS float atomics serialize PER LANE (~78 cyc) -> atomics dead; b64 RMW is the path.
// R19: occupancy 90% with 1-o-blocks REGRESSED (547 vs 363): 1.7x DS instructions.
//      DS instruction DENSITY ((k,ramp) 64-lane packing + cnt>32 gating) dominates;
//      occupancy beyond ~4 waves/SIMD buys nothing. float2 cell is load-bearing
//      (adjacent spikes make 4B-cell splits racy). Private planes floor: 9KB/wave.
// R20: revert to R14 structure (measured best 363) + two safe deltas:
//      (1) guard e8<EMAX8 replaces dustbin-min: sentinel spikes + missing B-pairs (27%)
//          exec-masked -> no bank cycles; PLANE 570->562.
//      (2) pub overlaid on dead acc cells (R19-validated, 2 extra barriers):
//          LDS 40,960 -> 35,968 -> 4 blocks/CU (16 waves vs 14).

#define NB 16
#define NI 512
#define NT 512
#define NO 1024
#define TOUT 529
#define SCAP 96           // spike capacity per (b,i); max observed ~48
#define OTILE 4
#define PLANE 562         // float2 cells 0..560 live; 562 for float4-divisible init
#define EMAX8 4488        // 561*8: first invalid byte offset
#define THETA_F 25.6f
#define BIAS_T 12.8f

// ---------- P1: spike list (LDS-staged) + packed byte-scaled words + counts + hist ----------
__global__ __launch_bounds__(256) void k_spikes(const float* __restrict__ x,
                                                unsigned short* __restrict__ slist,
                                                unsigned int* __restrict__ spkw,
                                                unsigned int* __restrict__ counts,
                                                float* __restrict__ hg) {
    __shared__ unsigned short sls[4][SCAP];
    int wq = threadIdx.x >> 6, lane = threadIdx.x & 63;
    int row = blockIdx.x * 4 + wq;                 // row = b*512 + i
    int b = row >> 9;
    const float* xr = x + (size_t)row * NT;
    for (int j = lane; j < SCAP; j += 64) sls[wq][j] = 0x1FFF;   // 0x1FFF<<3 = 0xFFF8 sentinel
    int base = 0;
    for (int kk = 0; kk < 8; ++kk) {
        int t = kk * 64 + lane;
        bool pred = xr[t] > 0.5f;
        unsigned long long mask = __ballot(pred);
        int pre = __popcll(mask & ((1ull << lane) - 1ull));
        int pos = base + pre;
        if (pred) {
            if (pos < SCAP) sls[wq][pos] = (unsigned short)t;
            unsafeAtomicAdd(&hg[b * NT + t], 1.0f);   // integer counts: exact any order
        }
        base += __popcll(mask);
    }
    __syncthreads();
    if (lane < SCAP / 2) {                         // full raw list for cold path
        unsigned v = (unsigned)sls[wq][2 * lane] | ((unsigned)sls[wq][2 * lane + 1] << 16);
        ((unsigned int*)(slist + (size_t)row * SCAP))[lane] = v;
    }
    if (lane < 32)                                 // packed (k, k+32) pair words, BYTE-scaled
        spkw[(size_t)row * 32 + lane] =
            ((unsigned)sls[wq][lane] << 3) | ((unsigned)sls[wq][lane + 32] << 19);
    if (lane == 0) counts[row] = (unsigned)min(base, SCAP);
}

// ---------- P2: per-(o,i) taps via candidate ranges (bit-identical to 50-iter loop) ----------
// tap[((o*512+i)*2 + ramp)] = float4(v1, v2, pos8_as_int_bits, 0). Missing pair: pos8=16384.
__device__ __forceinline__ float kval(float b15, int tau) {
    if (tau > 47) return 0.f;
    float f = (float)tau * 0.0625f;
    float g = b15 - (float)tau * 0.03125f;
    return fmaxf(0.f, fminf(f, g));
}

__global__ __launch_bounds__(256) void k_taps(const float* __restrict__ weight,
                                              float4* __restrict__ tap) {
    int p = blockIdx.x * 256 + threadIdx.x;        // 512*1024; i fast -> coalesced
    int o = p >> 9, i = p & 511;
    float w = weight[o * NI + i];
    float b15 = 1.5f * w;
    float vA1 = 0.f, vA2 = 0.f, vB1 = 0.f, vB2 = 0.f;
    int posA = 2048, posB = 2048, state = 0;
    // d(tau) nonzero only near the two kinks s1=16w, s2=48w (+-1 widened) and onset.
    int n1 = (int)floorf(16.0f * w);
    int n2 = (int)floorf(48.0f * w);
    int lo1 = max(n1, 1);
    int hi1, lo2, hi2;
    if (n2 <= n1 + 4) { hi1 = min(n2 + 3, 49); lo2 = 1; hi2 = 0; }   // merged, range2 empty
    else             { hi1 = min(n1 + 3, 49); lo2 = n2; hi2 = min(n2 + 3, 49); }

#define TAPRUN(LO, HI)                                                                \
    {                                                                                 \
        float Km1 = kval(b15, (LO) - 1), Km2 = kval(b15, (LO) - 2);                   \
        for (int tau = (LO); tau <= (HI); ++tau) {                                    \
            float K = kval(b15, tau);                                                 \
            float d = (K - Km1) - (Km1 - Km2);                                        \
            if (tau == 1) d -= 0.0625f;            /* onset -> histogram */           \
            if (d != 0.f) {                                                           \
                if (state == 0)      { posA = tau; vA1 = d; state = 1; }              \
                else if (state == 1) { if (tau == posA + 1) { vA2 = d; state = 2; }   \
                                       else { posB = tau; vB1 = d; state = 3; } }     \
                else if (state == 2) { posB = tau; vB1 = d; state = 3; }              \
                else if (state == 3) { if (tau == posB + 1) { vB2 = d; state = 4; } } \
            }                                                                         \
            Km2 = Km1; Km1 = K;                                                       \
        }                                                                             \
    }
    TAPRUN(lo1, hi1)
    if (lo2 <= hi2) TAPRUN(lo2, hi2)

    size_t base = 2 * ((size_t)o * NI + i);
    tap[base]     = make_float4(vA1, vA2, __int_as_float(posA >= 2048 ? 16384 : posA * 8), 0.f);
    tap[base + 1] = make_float4(vB1, vB2, __int_as_float(posB >= 2048 ? 16384 : posB * 8), 0.f);
}

// ---------- P3: wave-exclusive-plane float2 RMW scatter + fused double cumsum^2 ----------
// Wave w owns float2 planes (w,ramp0),(w,ramp1). Lane: k=lane>>1 spike slot, ramp=lane&1.
// cell = plane[e] = (v1_acc, v2_acc); v2 consumed with +1 shift at cumsum read.
// Non-atomic RMW race-free: within a plane all active lanes carry DISTINCT spike times.
// Guard e8<EMAX8 exec-masks sentinel slots (t8=0xFFF8) and missing pairs (p8=16384).
#define PROC(TP, WV, CNT, IDX)                                                        \
    {                                                                                 \
        const int p8 = __float_as_int((TP).z);                                        \
        {                                                                             \
            int e8 = (int)((WV) & 0xFFFFu) + p8;                                      \
            if (e8 < EMAX8) {                                                         \
                float2* cell = (float2*)((char*)accw + e8);                           \
                float2 v = *cell; v.x += (TP).x; v.y += (TP).y; *cell = v;            \
            }                                                                         \
        }                                                                             \
        if ((CNT) > 32u) {                                                            \
            int e8 = (int)((WV) >> 16) + p8;                                          \
            if (e8 < EMAX8) {                                                         \
                float2* cell = (float2*)((char*)accw + e8);                           \
                float2 v = *cell; v.x += (TP).x; v.y += (TP).y; *cell = v;            \
            }                                                                         \
        }                                                                             \
        if ((CNT) > 64u) {                                                            \
            const unsigned short* sr = slist + (size_t)(b * NI + (IDX)) * SCAP;       \
            for (int kk = 64 + k; kk < (int)(CNT); kk += 32) {                        \
                int e8 = ((int)sr[kk] << 3) + p8;                                     \
                if (e8 < EMAX8) {                                                     \
                    float2* cell = (float2*)((char*)accw + e8);                       \
                    float2 v = *cell; v.x += (TP).x; v.y += (TP).y; *cell = v;        \
                }                                                                     \
            }                                                                         \
        }                                                                             \
    }

__global__ __launch_bounds__(256, 4) void k_scatter(const unsigned short* __restrict__ slist,
                                                    const unsigned int* __restrict__ spkw,
                                                    const unsigned int* __restrict__ counts,
                                                    const float4* __restrict__ tap,
                                                    const float* __restrict__ hg,
                                                    float* __restrict__ pot) {
    __shared__ __align__(16) float2 acc[OTILE * 2 * PLANE];  // 35,968 B -> 4 blocks/CU
    const int o0 = blockIdx.x * OTILE;
    const int b  = blockIdx.y;
    const int tid = threadIdx.x;
    const int w = tid >> 6, lane = tid & 63;
    const int k = lane >> 1, ramp = lane & 1;

    for (int idx = tid; idx < OTILE * PLANE; idx += 256)     // 2248 float4s = whole acc
        ((float4*)acc)[idx] = make_float4(0.f, 0.f, 0.f, 0.f);
    __syncthreads();

    float2* accw = acc + (w * 2 + ramp) * PLANE;   // my (wave, ramp) plane
    const unsigned int* wrow = spkw + (size_t)(b * NI) * 32 + k;
    const float4* trow = tap + 2 * (size_t)(o0 + w) * NI + ramp;
    const uint4* crow = (const uint4*)(counts + b * NI);

    // prefetch quad 0 (statically-named scalars -> registers; R9 lesson)
    float4 ntA = trow[0], ntB = trow[2], ntC = trow[4], ntD = trow[6];
    unsigned nwA = wrow[0], nwB = wrow[32], nwC = wrow[64], nwD = wrow[96];
    uint4 ncc = crow[0];

    const int NIQ = NI / 4;
    for (int iq = 0; iq < NIQ; ++iq) {
        const float4 tA = ntA, tB = ntB, tC = ntC, tD = ntD;
        const unsigned wA = nwA, wB = nwB, wC = nwC, wD = nwD;
        const uint4 cc = ncc;
        if (iq + 1 < NIQ) {                        // prefetch next quad
            const float4* tb = trow + (size_t)(iq + 1) * 8;
            ntA = tb[0]; ntB = tb[2]; ntC = tb[4]; ntD = tb[6];
            const unsigned int* wb = wrow + (size_t)(iq + 1) * 128;
            nwA = wb[0]; nwB = wb[32]; nwC = wb[64]; nwD = wb[96];
            ncc = crow[iq + 1];
        }
        const int i0 = iq * 4;
        PROC(tA, wA, cc.x, i0)
        PROC(tB, wB, cc.y, i0 + 1)
        PROC(tC, wC, cc.z, i0 + 2)
        PROC(tD, wD, cc.w, i0 + 3)
    }
    __syncthreads();

    // ---- cumsum^2 (double): thread (oo=w, q=lane) owns cells [9q, 9q+9) ----
    const int q = lane;
    const float2* pr0 = acc + (w * 2) * PLANE;
    const float2* pr1 = pr0 + PLANE;
    const float* hb = hg + b * NT;
    double dsv[9];
    double s1d = 0.0, s2d = 0.0;
#pragma unroll
    for (int r = 0; r < 9; ++r) {
        int e = q * 9 + r;
        double d = 0.0;
        if (e < 561) {
            float2 c0 = pr0[e], c1 = pr1[e];
            d = (double)c0.x + (double)c1.x;
            if (e >= 1) {
                float2 m0 = pr0[e - 1], m1 = pr1[e - 1];
                d += (double)m0.y + (double)m1.y;           // v2 planes: shifted +1
                if (e <= 512) d += 0.0625 * (double)hb[e - 1];   // onset histogram
            }
        }
        dsv[r] = d; s1d += d; s2d += s1d;
    }
    __syncthreads();                               // all dsv reads done before pub overlay
    double* pub = (double*)acc;                    // overlays plane-0 cells 0..511 (dead)
    pub[2 * tid] = s1d; pub[2 * tid + 1] = s2d;
    __syncthreads();
    if (tid < 4) {                                 // serial carry scan per o-row
        double c1 = 0.0, c2 = 0.0;
        for (int qq = 0; qq < 64; ++qq) {
            int j = (tid << 6) + qq;
            double S1 = pub[2 * j], S2 = pub[2 * j + 1];
            pub[2 * j] = c1; pub[2 * j + 1] = c2;
            c2 += 9.0 * c1 + S2;
            c1 += S1;
        }
    }
    __syncthreads();
    const double C1 = pub[2 * tid], C2 = pub[2 * tid + 1];
    __syncthreads();                               // pub reads done before .x writes clobber
    {
        double a1 = 0.0, a2 = 0.0;
        float2* rowW = acc + (w * 2) * PLANE;
#pragma unroll
        for (int r = 0; r < 9; ++r) {
            a1 += dsv[r]; a2 += a1;
            int e = q * 9 + r;
            if (e < 561) rowW[e].x = (float)(C2 + C1 * (double)(r + 1) + a2);
        }
    }
    __syncthreads();
    for (int oo = 0; oo < OTILE; ++oo)             // coalesced pot write (t fastest)
        for (int t = tid; t < TOUT; t += 256)
            pot[((size_t)(b * NO + o0 + oo)) * TOUT + t] = acc[(oo * 2) * PLANE + t + 15].x + BIAS_T;
}

// ---------- P4a: partial argmax over 128-o chunks (1152 blocks) ----------
__global__ __launch_bounds__(256) void k_argmax1(const float* __restrict__ pot,
                                                 float* __restrict__ pval,
                                                 unsigned short* __restrict__ pidx) {
    __shared__ float sv[4][64];
    __shared__ int   si[4][64];
    int b = blockIdx.y, c = blockIdx.z;
    int lane = threadIdx.x & 63, grp = threadIdx.x >> 6;
    int t = blockIdx.x * 64 + lane;
    bool valid = t < TOUT;
    float best = -1.f; int bidx = 0;
    if (valid) {
        int ob = c * 128 + grp * 32;
        for (int od = 0; od < 32; ++od) {          // ascending o + strict '>' => first max wins
            int o = ob + od;
            float v = pot[((size_t)(b * NO + o)) * TOUT + t];
            if (v > best) { best = v; bidx = o; }
        }
    }
    sv[grp][lane] = best; si[grp][lane] = bidx;
    __syncthreads();
    if (grp == 0 && valid) {
#pragma unroll
        for (int g = 1; g < 4; ++g) {              // ascending grp = ascending o
            float v = sv[g][lane];
            if (v > best) { best = v; bidx = si[g][lane]; }
        }
        pval[((size_t)(c * NB + b)) * TOUT + t] = best;
        pidx[((size_t)(c * NB + b)) * TOUT + t] = (unsigned short)bidx;
    }
}

// ---------- P4b: combine 8 chunks ----------
__global__ __launch_bounds__(64) void k_argmax2(const float* __restrict__ pval,
                                                const unsigned short* __restrict__ pidx,
                                                float* __restrict__ aval,
                                                unsigned short* __restrict__ aidx) {
    int b = blockIdx.y;
    int t = blockIdx.x * 64 + threadIdx.x;
    if (t >= TOUT) return;
    float best = -1.f; int bidx = 0;
#pragma unroll
    for (int c = 0; c < 8; ++c) {                  // ascending chunk = ascending o
        size_t idx = ((size_t)(c * NB + b)) * TOUT + t;
        float v = pval[idx];
        if (v > best) { best = v; bidx = pidx[idx]; }
    }
    aval[t * NB + b] = best;
    aidx[t * NB + b] = (unsigned short)bidx;
}

// ---------- P5: serial refractory scan (depression uniform across neurons) ----------
__global__ __launch_bounds__(256) void k_wta(const float* __restrict__ aval,
                                             const unsigned short* __restrict__ aidx,
                                             float* __restrict__ out) {
    __shared__ float lv[TOUT * NB];
    __shared__ unsigned short li[TOUT * NB];
    for (int idx = threadIdx.x; idx < TOUT * NB; idx += 256) { lv[idx] = aval[idx]; li[idx] = aidx[idx]; }
    __syncthreads();
    int b = threadIdx.x;
    if (b < NB) {
        int r = 0;
        for (int t = 0; t < TOUT; ++t) {
            float v = lv[t * NB + b];
            if (r == 0 && v > THETA_F) {
                int n = (int)li[t * NB + b];
                out[((size_t)(b * NO + n)) * TOUT + t] = 1.0f;
                r = 48;
            }
            r = max(r - 1, 0);
        }
    }
}

extern "C" void kernel_launch(void* const* d_in, const int* in_sizes, int n_in,
                              void* d_out, int out_size, void* d_ws, size_t ws_size,
                              hipStream_t stream) {
    const float* x      = (const float*)d_in[0];   // [16,1,512,512]
    const float* weight = (const float*)d_in[1];   // [1024,512]
    float* out = (float*)d_out;                    // [16,1,1024,529]
    char* ws = (char*)d_ws;
    // ws layout (~19.9 MB)
    unsigned short* slist  = (unsigned short*)(ws);            // 8192*96*2     = 1,572,864
    unsigned int*   spkw   = (unsigned int*)(ws + 1572864);    // 8192*32*4     = 1,048,576
    unsigned int*   counts = (unsigned int*)(ws + 2621440);    // 8192*4        = 32,768
    float4*         tap    = (float4*)(ws + 2654208);          // 1024*512*2*16 = 16,777,216
    float*          hg     = (float*)(ws + 19431424);          // 16*512*4      = 32,768
    float*          aval   = (float*)(ws + 19464192);          // 529*16*4      = 33,856
    unsigned short* aidx   = (unsigned short*)(ws + 19498048); // 529*16*2      = 16,928
    float*          pval   = (float*)(ws + 19514976);          // 8*16*529*4    = 270,848
    unsigned short* pidx   = (unsigned short*)(ws + 19785824); // 8*16*529*2    = 135,424

    hipMemsetAsync(hg, 0, NB * NT * sizeof(float), stream);    // before k_spikes (hist fused)
    k_spikes<<<2048, 256, 0, stream>>>(x, slist, spkw, counts, hg);
    k_taps<<<2048, 256, 0, stream>>>(weight, tap);
    k_scatter<<<dim3(NO / OTILE, NB), 256, 0, stream>>>(slist, spkw, counts, tap, hg, out);
    k_argmax1<<<dim3(9, NB, 8), 256, 0, stream>>>(out, pval, pidx);
    k_argmax2<<<dim3(9, NB), 64, 0, stream>>>(pval, pidx, aval, aidx);
    hipMemsetAsync(d_out, 0, (size_t)out_size * sizeof(float), stream);   // clear pot
    k_wta<<<1, 256, 0, stream>>>(aval, aidx, out);                        // write spikes
}

// Round 12
// 491.032 us; speedup vs baseline: 8.8750x; 1.0766x over previous
//
#include <hip/hip_runtime.h>
#include <stdint.h>

// Sizes: x [16,1,512,512] f32 binary; weight [1024,512] f32; out [16,1,1024,529] f32.
// pot[b,o,t'] = sum_tau K(w[o,i],tau) * x[b,i,t'+15-tau] + 12.8
// K via cumsum^2 of its Delta^2; tap pairs scattered at spike positions into per-(wave,ramp)
// float2 LDS planes; WTA depression uniform -> per-batch serial scan.
// Ledger: R14 scatter (dustbin-min, 4 blk/CU) = 363us measured best.
//   R12: fixed layout permutations can't change random-index bank histogram (null).
//   R10/R16: LDS atomics serialize per lane (~78 cyc) -> dead.
//   R19: occupancy 90% regressed (DS instruction density dominates).
//   R20: exec-mask guard per RMW costs more than dustbin bank cycles (404 vs 363);
//        R14 was already at 4 blocks/CU (40,960 = 160K/4 exactly).
// R21: k_scatter reverted BYTE-IDENTICAL to R14. New lever: DATA-DEPENDENT bank
// balance. bank-pair = (t+p) mod 16 with wave-uniform p => determined by spike t.
// k_spikes now emits each row's spikes round-robin by t mod 16 (counting-sort
// permutation: rank-in-class major, class minor): any aligned <=16-slot run has
// distinct t mod 16 -> <=2-3 accesses per bank-pair vs ~4.5 random. Bit-exact
// (slot permutation: distinct t -> distinct cells within an i). Tail (>64) keeps
// original order for overflow-path consistency.

#define NB 16
#define NI 512
#define NT 512
#define NO 1024
#define TOUT 529
#define SCAP 96           // spike capacity per (b,i); max observed ~48
#define OTILE 4
#define PLANE 570         // cells 0..560 live, 561..568 spread dustbin, pad->570
#define THETA_F 25.6f
#define BIAS_T 12.8f

// ---------- P1: spike list + mod-16 round-robin permutation + packed words + hist ----------
__global__ __launch_bounds__(256) void k_spikes(const float* __restrict__ x,
                                                unsigned short* __restrict__ slist,
                                                unsigned int* __restrict__ spkw,
                                                unsigned int* __restrict__ counts,
                                                float* __restrict__ hg) {
    __shared__ unsigned short sls[4][SCAP];
    __shared__ unsigned short sls2[4][SCAP];
    int wq = threadIdx.x >> 6, lane = threadIdx.x & 63;
    int row = blockIdx.x * 4 + wq;                 // row = b*512 + i
    int b = row >> 9;
    const float* xr = x + (size_t)row * NT;
    for (int j = lane; j < SCAP; j += 64) { sls[wq][j] = 0x1FFF; sls2[wq][j] = 0x1FFF; }
    int base = 0;                                  // wave-uniform (ballot-accumulated)
    for (int kk = 0; kk < 8; ++kk) {
        int t = kk * 64 + lane;
        bool pred = xr[t] > 0.5f;
        unsigned long long mask = __ballot(pred);
        int pre = __popcll(mask & ((1ull << lane) - 1ull));
        int pos = base + pre;
        if (pred) {
            if (pos < SCAP) sls[wq][pos] = (unsigned short)t;
            unsafeAtomicAdd(&hg[b * NT + t], 1.0f);   // integer counts: exact any order
        }
        base += __popcll(mask);
    }
    __syncthreads();
    const int cnt = min(base, SCAP);
    const int m = min(cnt, 64);                    // permute first m; tail keeps order
    // counting-sort permutation: key = (rank_in_class, class), class = t & 15.
    unsigned short myt = sls[wq][lane];            // lane j = element j (j<m valid)
    int cls = myt & 15;
    unsigned long long below = (1ull << lane) - 1ull;
    int cntc[16];
    int r = 0;
#pragma unroll
    for (int c = 0; c < 16; ++c) {
        unsigned long long mc = __ballot(lane < m && cls == c);
        cntc[c] = __popcll(mc);
        if (cls == c) r = __popcll(mc & below);
    }
    int rank = 0;
#pragma unroll
    for (int c = 0; c < 16; ++c) {
        rank += min(cntc[c], r);                   // elements with smaller rank
        if (c < cls && cntc[c] > r) rank += 1;     // same rank, smaller class
    }
    if (lane < m) sls2[wq][rank] = myt;
    for (int j = 64 + lane; j < cnt; j += 64) sls2[wq][j] = sls[wq][j];   // tail as-is
    __syncthreads();
    if (lane < SCAP / 2) {                         // permuted full list for cold path
        unsigned v = (unsigned)sls2[wq][2 * lane] | ((unsigned)sls2[wq][2 * lane + 1] << 16);
        ((unsigned int*)(slist + (size_t)row * SCAP))[lane] = v;
    }
    if (lane < 32)                                 // packed (k, k+32) pair words, BYTE-scaled
        spkw[(size_t)row * 32 + lane] =
            ((unsigned)sls2[wq][lane] << 3) | ((unsigned)sls2[wq][lane + 32] << 19);
    if (lane == 0) counts[row] = (unsigned)cnt;
}

// ---------- P2: per-(o,i) taps via candidate ranges (bit-identical to 50-iter loop) ----------
// tap[((o*512+i)*2 + ramp)] = float4(v1, v2, pos8_as_int_bits, 0). Missing pair: pos8=16384.
__device__ __forceinline__ float kval(float b15, int tau) {
    if (tau > 47) return 0.f;
    float f = (float)tau * 0.0625f;
    float g = b15 - (float)tau * 0.03125f;
    return fmaxf(0.f, fminf(f, g));
}

__global__ __launch_bounds__(256) void k_taps(const float* __restrict__ weight,
                                              float4* __restrict__ tap) {
    int p = blockIdx.x * 256 + threadIdx.x;        // 512*1024; i fast -> coalesced
    int o = p >> 9, i = p & 511;
    float w = weight[o * NI + i];
    float b15 = 1.5f * w;
    float vA1 = 0.f, vA2 = 0.f, vB1 = 0.f, vB2 = 0.f;
    int posA = 2048, posB = 2048, state = 0;
    // d(tau) nonzero only near the two kinks s1=16w, s2=48w (+-1 widened) and onset.
    int n1 = (int)floorf(16.0f * w);
    int n2 = (int)floorf(48.0f * w);
    int lo1 = max(n1, 1);
    int hi1, lo2, hi2;
    if (n2 <= n1 + 4) { hi1 = min(n2 + 3, 49); lo2 = 1; hi2 = 0; }   // merged, range2 empty
    else             { hi1 = min(n1 + 3, 49); lo2 = n2; hi2 = min(n2 + 3, 49); }

#define TAPRUN(LO, HI)                                                                \
    {                                                                                 \
        float Km1 = kval(b15, (LO) - 1), Km2 = kval(b15, (LO) - 2);                   \
        for (int tau = (LO); tau <= (HI); ++tau) {                                    \
            float K = kval(b15, tau);                                                 \
            float d = (K - Km1) - (Km1 - Km2);                                        \
            if (tau == 1) d -= 0.0625f;            /* onset -> histogram */           \
            if (d != 0.f) {                                                           \
                if (state == 0)      { posA = tau; vA1 = d; state = 1; }              \
                else if (state == 1) { if (tau == posA + 1) { vA2 = d; state = 2; }   \
                                       else { posB = tau; vB1 = d; state = 3; } }     \
                else if (state == 2) { posB = tau; vB1 = d; state = 3; }              \
                else if (state == 3) { if (tau == posB + 1) { vB2 = d; state = 4; } } \
            }                                                                         \
            Km2 = Km1; Km1 = K;                                                       \
        }                                                                             \
    }
    TAPRUN(lo1, hi1)
    if (lo2 <= hi2) TAPRUN(lo2, hi2)

    size_t base = 2 * ((size_t)o * NI + i);
    tap[base]     = make_float4(vA1, vA2, __int_as_float(posA >= 2048 ? 16384 : posA * 8), 0.f);
    tap[base + 1] = make_float4(vB1, vB2, __int_as_float(posB >= 2048 ? 16384 : posB * 8), 0.f);
}

// ---------- P3: wave-exclusive-plane float2 RMW scatter (BYTE-IDENTICAL to R14) ----------
// Wave w owns float2 planes (w,ramp0),(w,ramp1). Lane: k=lane>>1 spike slot, ramp=lane&1.
// Byte addressing: e8 = min(t8 + p8, dcap8); dcap8 = (561+(k&7))*8 spread dustbin.
// Non-atomic RMW race-free: distinct spike times per lane within a plane.
#define PROC(TP, WV, CNT, IDX)                                                        \
    {                                                                                 \
        const int p8 = __float_as_int((TP).z);                                        \
        {                                                                             \
            int e8 = min((int)((WV) & 0xFFFFu) + p8, dcap8);                          \
            float2* cell = (float2*)((char*)accw + e8);                               \
            float2 v = *cell; v.x += (TP).x; v.y += (TP).y; *cell = v;                \
        }                                                                             \
        if ((CNT) > 32u) {                                                            \
            int e8 = min((int)((WV) >> 16) + p8, dcap8);                              \
            float2* cell = (float2*)((char*)accw + e8);                               \
            float2 v = *cell; v.x += (TP).x; v.y += (TP).y; *cell = v;                \
        }                                                                             \
        if ((CNT) > 64u) {                                                            \
            const unsigned short* sr = slist + (size_t)(b * NI + (IDX)) * SCAP;       \
            for (int kk = 64 + k; kk < (int)(CNT); kk += 32) {                        \
                int e8 = min(((int)sr[kk] << 3) + p8, dcap8);                         \
                float2* cell = (float2*)((char*)accw + e8);                           \
                float2 v = *cell; v.x += (TP).x; v.y += (TP).y; *cell = v;            \
            }                                                                         \
        }                                                                             \
    }

__global__ __launch_bounds__(256, 4) void k_scatter(const unsigned short* __restrict__ slist,
                                                    const unsigned int* __restrict__ spkw,
                                                    const unsigned int* __restrict__ counts,
                                                    const float4* __restrict__ tap,
                                                    const float* __restrict__ hg,
                                                    float* __restrict__ pot) {
    __shared__ __align__(16) float2 acc[OTILE * 2 * PLANE];  // 36,480 B
    __shared__ double pub[512];                              // 4,096 B -> 40,832: 4 blk/CU
    const int o0 = blockIdx.x * OTILE;
    const int b  = blockIdx.y;
    const int tid = threadIdx.x;
    const int w = tid >> 6, lane = tid & 63;
    const int k = lane >> 1, ramp = lane & 1;
    const int dcap8 = (561 + (k & 7)) * 8;         // spread dustbin, loop-invariant

    for (int idx = tid; idx < OTILE * PLANE; idx += 256)     // 2280 float4s = whole acc
        ((float4*)acc)[idx] = make_float4(0.f, 0.f, 0.f, 0.f);
    __syncthreads();

    float2* accw = acc + (w * 2 + ramp) * PLANE;   // my (wave, ramp) plane
    const unsigned int* wrow = spkw + (size_t)(b * NI) * 32 + k;
    const float4* trow = tap + 2 * (size_t)(o0 + w) * NI + ramp;
    const uint4* crow = (const uint4*)(counts + b * NI);

    // prefetch quad 0 (statically-named scalars -> registers; R9 lesson)
    float4 ntA = trow[0], ntB = trow[2], ntC = trow[4], ntD = trow[6];
    unsigned nwA = wrow[0], nwB = wrow[32], nwC = wrow[64], nwD = wrow[96];
    uint4 ncc = crow[0];

    const int NIQ = NI / 4;
    for (int iq = 0; iq < NIQ; ++iq) {
        const float4 tA = ntA, tB = ntB, tC = ntC, tD = ntD;
        const unsigned wA = nwA, wB = nwB, wC = nwC, wD = nwD;
        const uint4 cc = ncc;
        if (iq + 1 < NIQ) {                        // prefetch next quad
            const float4* tb = trow + (size_t)(iq + 1) * 8;
            ntA = tb[0]; ntB = tb[2]; ntC = tb[4]; ntD = tb[6];
            const unsigned int* wb = wrow + (size_t)(iq + 1) * 128;
            nwA = wb[0]; nwB = wb[32]; nwC = wb[64]; nwD = wb[96];
            ncc = crow[iq + 1];
        }
        const int i0 = iq * 4;
        PROC(tA, wA, cc.x, i0)
        PROC(tB, wB, cc.y, i0 + 1)
        PROC(tC, wC, cc.z, i0 + 2)
        PROC(tD, wD, cc.w, i0 + 3)
    }
    __syncthreads();

    // ---- cumsum^2 (double): thread (oo=w, q=lane) owns cells [9q, 9q+9) ----
    const int q = lane;
    const float2* pr0 = acc + (w * 2) * PLANE;
    const float2* pr1 = pr0 + PLANE;
    const float* hb = hg + b * NT;
    double dsv[9];
    double s1d = 0.0, s2d = 0.0;
#pragma unroll
    for (int r = 0; r < 9; ++r) {
        int e = q * 9 + r;
        double d = 0.0;
        if (e < 561) {
            float2 c0 = pr0[e], c1 = pr1[e];
            d = (double)c0.x + (double)c1.x;
            if (e >= 1) {
                float2 m0 = pr0[e - 1], m1 = pr1[e - 1];
                d += (double)m0.y + (double)m1.y;           // v2 planes: shifted +1
                if (e <= 512) d += 0.0625 * (double)hb[e - 1];   // onset histogram
            }
        }
        dsv[r] = d; s1d += d; s2d += s1d;
    }
    pub[2 * tid] = s1d; pub[2 * tid + 1] = s2d;
    __syncthreads();
    if (tid < 4) {                                 // serial carry scan per o-row
        double c1 = 0.0, c2 = 0.0;
        for (int qq = 0; qq < 64; ++qq) {
            int j = (tid << 6) + qq;
            double S1 = pub[2 * j], S2 = pub[2 * j + 1];
            pub[2 * j] = c1; pub[2 * j + 1] = c2;
            c2 += 9.0 * c1 + S2;
            c1 += S1;
        }
    }
    __syncthreads();
    {
        const double C1 = pub[2 * tid], C2 = pub[2 * tid + 1];
        double a1 = 0.0, a2 = 0.0;
        float2* rowW = acc + (w * 2) * PLANE;
#pragma unroll
        for (int r = 0; r < 9; ++r) {
            a1 += dsv[r]; a2 += a1;
            int e = q * 9 + r;
            if (e < 561) rowW[e].x = (float)(C2 + C1 * (double)(r + 1) + a2);
        }
    }
    __syncthreads();
    for (int oo = 0; oo < OTILE; ++oo)             // coalesced pot write (t fastest)
        for (int t = tid; t < TOUT; t += 256)
            pot[((size_t)(b * NO + o0 + oo)) * TOUT + t] = acc[(oo * 2) * PLANE + t + 15].x + BIAS_T;
}

// ---------- P4a: partial argmax over 128-o chunks (1152 blocks) ----------
__global__ __launch_bounds__(256) void k_argmax1(const float* __restrict__ pot,
                                                 float* __restrict__ pval,
                                                 unsigned short* __restrict__ pidx) {
    __shared__ float sv[4][64];
    __shared__ int   si[4][64];
    int b = blockIdx.y, c = blockIdx.z;
    int lane = threadIdx.x & 63, grp = threadIdx.x >> 6;
    int t = blockIdx.x * 64 + lane;
    bool valid = t < TOUT;
    float best = -1.f; int bidx = 0;
    if (valid) {
        int ob = c * 128 + grp * 32;
        for (int od = 0; od < 32; ++od) {          // ascending o + strict '>' => first max wins
            int o = ob + od;
            float v = pot[((size_t)(b * NO + o)) * TOUT + t];
            if (v > best) { best = v; bidx = o; }
        }
    }
    sv[grp][lane] = best; si[grp][lane] = bidx;
    __syncthreads();
    if (grp == 0 && valid) {
#pragma unroll
        for (int g = 1; g < 4; ++g) {              // ascending grp = ascending o
            float v = sv[g][lane];
            if (v > best) { best = v; bidx = si[g][lane]; }
        }
        pval[((size_t)(c * NB + b)) * TOUT + t] = best;
        pidx[((size_t)(c * NB + b)) * TOUT + t] = (unsigned short)bidx;
    }
}

// ---------- P4b: combine 8 chunks ----------
__global__ __launch_bounds__(64) void k_argmax2(const float* __restrict__ pval,
                                                const unsigned short* __restrict__ pidx,
                                                float* __restrict__ aval,
                                                unsigned short* __restrict__ aidx) {
    int b = blockIdx.y;
    int t = blockIdx.x * 64 + threadIdx.x;
    if (t >= TOUT) return;
    float best = -1.f; int bidx = 0;
#pragma unroll
    for (int c = 0; c < 8; ++c) {                  // ascending chunk = ascending o
        size_t idx = ((size_t)(c * NB + b)) * TOUT + t;
        float v = pval[idx];
        if (v > best) { best = v; bidx = pidx[idx]; }
    }
    aval[t * NB + b] = best;
    aidx[t * NB + b] = (unsigned short)bidx;
}

// ---------- P5: serial refractory scan (depression uniform across neurons) ----------
__global__ __launch_bounds__(256) void k_wta(const float* __restrict__ aval,
                                             const unsigned short* __restrict__ aidx,
                                             float* __restrict__ out) {
    __shared__ float lv[TOUT * NB];
    __shared__ unsigned short li[TOUT * NB];
    for (int idx = threadIdx.x; idx < TOUT * NB; idx += 256) { lv[idx] = aval[idx]; li[idx] = aidx[idx]; }
    __syncthreads();
    int b = threadIdx.x;
    if (b < NB) {
        int r = 0;
        for (int t = 0; t < TOUT; ++t) {
            float v = lv[t * NB + b];
            if (r == 0 && v > THETA_F) {
                int n = (int)li[t * NB + b];
                out[((size_t)(b * NO + n)) * TOUT + t] = 1.0f;
                r = 48;
            }
            r = max(r - 1, 0);
        }
    }
}

extern "C" void kernel_launch(void* const* d_in, const int* in_sizes, int n_in,
                              void* d_out, int out_size, void* d_ws, size_t ws_size,
                              hipStream_t stream) {
    const float* x      = (const float*)d_in[0];   // [16,1,512,512]
    const float* weight = (const float*)d_in[1];   // [1024,512]
    float* out = (float*)d_out;                    // [16,1,1024,529]
    char* ws = (char*)d_ws;
    // ws layout (~19.9 MB)
    unsigned short* slist  = (unsigned short*)(ws);            // 8192*96*2     = 1,572,864
    unsigned int*   spkw   = (unsigned int*)(ws + 1572864);    // 8192*32*4     = 1,048,576
    unsigned int*   counts = (unsigned int*)(ws + 2621440);    // 8192*4        = 32,768
    float4*         tap    = (float4*)(ws + 2654208);          // 1024*512*2*16 = 16,777,216
    float*          hg     = (float*)(ws + 19431424);          // 16*512*4      = 32,768
    float*          aval   = (float*)(ws + 19464192);          // 529*16*4      = 33,856
    unsigned short* aidx   = (unsigned short*)(ws + 19498048); // 529*16*2      = 16,928
    float*          pval   = (float*)(ws + 19514976);          // 8*16*529*4    = 270,848
    unsigned short* pidx   = (unsigned short*)(ws + 19785824); // 8*16*529*2    = 135,424

    hipMemsetAsync(hg, 0, NB * NT * sizeof(float), stream);    // before k_spikes (hist fused)
    k_spikes<<<2048, 256, 0, stream>>>(x, slist, spkw, counts, hg);
    k_taps<<<2048, 256, 0, stream>>>(weight, tap);
    k_scatter<<<dim3(NO / OTILE, NB), 256, 0, stream>>>(slist, spkw, counts, tap, hg, out);
    k_argmax1<<<dim3(9, NB, 8), 256, 0, stream>>>(out, pval, pidx);
    k_argmax2<<<dim3(9, NB), 64, 0, stream>>>(pval, pidx, aval, aidx);
    hipMemsetAsync(d_out, 0, (size_t)out_size * sizeof(float), stream);   // clear pot
    k_wta<<<1, 256, 0, stream>>>(aval, aidx, out);                        // write spikes
}